// Round 1
// baseline (762.147 us; speedup 1.0000x reference)
//
#include <hip/hip_runtime.h>

typedef __bf16 bf16_t;
typedef __bf16 bf16x4 __attribute__((ext_vector_type(4)));
typedef __bf16 bf16x8 __attribute__((ext_vector_type(8)));
typedef float f32x4 __attribute__((ext_vector_type(4)));

#define GLL16(gp, lp) __builtin_amdgcn_global_load_lds( \
    (__attribute__((address_space(1))) void*)(gp),      \
    (__attribute__((address_space(3))) void*)(lp), 16, 0, 0)

// ---------------------------------------------------------------------------
// GEMM: C[M,N] = epi(A[M,K] @ W[N,K]^T + bias)
// 128x128 tile, BK=64, 256 threads = 4 waves (2x2), each wave 64x64 out.
// EPI: 0 = relu->bf16, 1 = bias->bf16, 2 = sigmoid(U)*v->bf16, 3 = bias->f32
// ---------------------------------------------------------------------------
template<int EPI>
__global__ __launch_bounds__(256, 2)
void gemm_bt(const bf16_t* __restrict__ A, int lda,
             const bf16_t* __restrict__ W,
             const float* __restrict__ bias,
             const bf16_t* __restrict__ Usig,
             void* __restrict__ Cv, int ldc, int K)
{
    __shared__ bf16_t As[128 * 64];
    __shared__ bf16_t Bs[128 * 64];
    const int t = threadIdx.x;
    const int w = t >> 6, l = t & 63;
    const int wr = w >> 1, wc = w & 1;

    const bf16_t* Ab = A + (size_t)blockIdx.y * 128 * lda;
    const bf16_t* Wb = W + (size_t)blockIdx.x * 128 * K;

    const bf16_t* asrc[4];
    const bf16_t* bsrc[4];
#pragma unroll
    for (int r = 0; r < 4; ++r) {
        const int seg = r * 256 + t;          // 1024 segs of 16B per tile
        asrc[r] = Ab + (size_t)(seg >> 3) * lda + (seg & 7) * 8;
        bsrc[r] = Wb + (size_t)(seg >> 3) * K   + (seg & 7) * 8;
    }

    f32x4 acc[4][4] = {};

    for (int kt = 0; kt < K; kt += 64) {
#pragma unroll
        for (int r = 0; r < 4; ++r) {
            GLL16(asrc[r], As + (r * 256 + w * 64) * 8);
            GLL16(bsrc[r], Bs + (r * 256 + w * 64) * 8);
            asrc[r] += 64;
            bsrc[r] += 64;
        }
        __syncthreads();   // compiler emits vmcnt(0) drain before barrier
#pragma unroll
        for (int kk = 0; kk < 2; ++kk) {
            const int ro = l & 15;
            const int ko = kk * 32 + (l >> 4) * 8;
            bf16x8 af[4], bq[4];
#pragma unroll
            for (int m = 0; m < 4; ++m)
                af[m] = *(const bf16x8*)(As + (wr * 64 + m * 16 + ro) * 64 + ko);
#pragma unroll
            for (int n = 0; n < 4; ++n)
                bq[n] = *(const bf16x8*)(Bs + (wc * 64 + n * 16 + ro) * 64 + ko);
#pragma unroll
            for (int m = 0; m < 4; ++m)
#pragma unroll
                for (int n = 0; n < 4; ++n)
                    acc[m][n] = __builtin_amdgcn_mfma_f32_16x16x32_bf16(
                        af[m], bq[n], acc[m][n], 0, 0, 0);
        }
        __syncthreads();
    }

    // epilogue: C/D frag layout col=lane&15, row=(lane>>4)*4+j  [guide m89]
    const int rbase = blockIdx.y * 128 + wr * 64 + ((l >> 4) << 2);
    const int cbase = blockIdx.x * 128 + wc * 64 + (l & 15);
#pragma unroll
    for (int n = 0; n < 4; ++n) {
        const int col = cbase + n * 16;
        const float bcol = bias[col];
#pragma unroll
        for (int m = 0; m < 4; ++m) {
#pragma unroll
            for (int j = 0; j < 4; ++j) {
                const int row = rbase + m * 16 + j;
                float v = acc[m][n][j] + bcol;
                if (EPI == 0) v = fmaxf(v, 0.0f);
                if (EPI == 2) {
                    const float u = (float)Usig[(size_t)row * ldc + col];
                    v *= 1.0f / (1.0f + __expf(-u));
                }
                if (EPI == 3) ((float*)Cv)[(size_t)row * ldc + col] = v;
                else          ((bf16_t*)Cv)[(size_t)row * ldc + col] = (bf16_t)v;
            }
        }
    }
}

// ---------------------------------------------------------------------------
struct WSrcs { const float* p[10]; };

__global__ __launch_bounds__(256)
void cast_weights(WSrcs srcs, bf16_t* __restrict__ dst)
{
    const int region = blockIdx.x >> 10;                 // 1024 blocks / 1M region
    const float* src = srcs.p[region];
    const size_t base = (size_t)(blockIdx.x & 1023) * 1024 + threadIdx.x * 4;
    const float4 f = *(const float4*)(src + base);
    bf16x4 h = {(bf16_t)f.x, (bf16_t)f.y, (bf16_t)f.z, (bf16_t)f.w};
    *(bf16x4*)(dst + ((size_t)region << 20) + base) = h;
}

__global__ __launch_bounds__(256)
void cast_act(const float* __restrict__ src, bf16_t* __restrict__ dst)
{
    const size_t i = ((size_t)blockIdx.x * 256 + threadIdx.x) * 4;
    const float4 f = *(const float4*)(src + i);
    bf16x4 h = {(bf16_t)f.x, (bf16_t)f.y, (bf16_t)f.z, (bf16_t)f.w};
    *(bf16x4*)(dst + i) = h;
}

__global__ __launch_bounds__(256)
void concat_bias(const float* __restrict__ a, const float* __restrict__ b,
                 float* __restrict__ dst)
{
    const int i = blockIdx.x * 256 + threadIdx.x;
    if (i < 1024) dst[i] = a[i];
    else if (i < 2048) dst[i] = b[i - 1024];
}

// ---------------------------------------------------------------------------
// One block per row: dual l2norm + sigmoid gate + exact top-80 (radix select
// on abs bits, stable lowest-index tie-break) + sparse write + visual concat.
// ---------------------------------------------------------------------------
__global__ __launch_bounds__(256)
void finalize_topk(float* __restrict__ AgF,      // OUT2: in Ag, out final
                   float* __restrict__ AlF,      // OUT3: in Al, out f2
                   const float* __restrict__ VIS,
                   float* __restrict__ O1)
{
    const int row = blockIdx.x, t = threadIdx.x;
    __shared__ int bins[256];
    __shared__ int sscan[256];
    __shared__ float wred[8];
    __shared__ int s_sel, s_kk;

    float* agp = AgF + (size_t)row * 1024 + t * 4;
    float* alp = AlF + (size_t)row * 1024 + t * 4;
    const float4 a4 = *(const float4*)agp;
    const float4 l4 = *(const float4*)alp;
    float av[4] = {a4.x, a4.y, a4.z, a4.w};
    float lv[4] = {l4.x, l4.y, l4.z, l4.w};
    float sa = 0.0f, sb = 0.0f;
#pragma unroll
    for (int j = 0; j < 4; ++j) { sa += av[j] * av[j]; sb += lv[j] * lv[j]; }
#pragma unroll
    for (int o = 32; o > 0; o >>= 1) {
        sa += __shfl_down(sa, o);
        sb += __shfl_down(sb, o);
    }
    if ((t & 63) == 0) { wred[t >> 6] = sa; wred[4 + (t >> 6)] = sb; }
    __syncthreads();
    const float sca = 1.0f / fmaxf(sqrtf(wred[0] + wred[1] + wred[2] + wred[3]), 1e-12f);
    const float scl = 1.0f / fmaxf(sqrtf(wred[4] + wred[5] + wred[6] + wred[7]), 1e-12f);

    float fv[4], f2v[4];
    unsigned ab[4];
#pragma unroll
    for (int j = 0; j < 4; ++j) {
        const float f2 = lv[j] * scl;
        const float f1 = av[j] * sca;
        const float fin = f2 / (1.0f + __expf(-f1));   // sigmoid(f1)*f2
        f2v[j] = f2; fv[j] = fin;
        ab[j] = __float_as_uint(fin) & 0x7fffffffu;
    }
    *(float4*)alp = make_float4(f2v[0], f2v[1], f2v[2], f2v[3]);
    *(float4*)agp = make_float4(fv[0], fv[1], fv[2], fv[3]);

    const float* vr = VIS + (size_t)row * 2048;
    float* o1r = O1 + (size_t)row * 3072;
    *(float4*)(o1r + t * 4)        = *(const float4*)(vr + t * 4);
    *(float4*)(o1r + 1024 + t * 4) = *(const float4*)(vr + 1024 + t * 4);

    // --- radix select: exact bits of the 80th-largest |fin| ---
    unsigned pref = 0u, msk = 0u;
    int kk = 80;
    for (int bp = 3; bp >= 0; --bp) {
        bins[t] = 0;
        __syncthreads();
#pragma unroll
        for (int j = 0; j < 4; ++j)
            if ((ab[j] & msk) == pref)
                atomicAdd(&bins[(ab[j] >> (bp * 8)) & 255], 1);
        __syncthreads();
        sscan[t] = bins[t];
        __syncthreads();
        for (int o = 1; o < 256; o <<= 1) {           // suffix sum
            const int add = (t + o < 256) ? sscan[t + o] : 0;
            __syncthreads();
            sscan[t] += add;
            __syncthreads();
        }
        const int Sme = sscan[t];
        const int Snx = (t < 255) ? sscan[t + 1] : 0;
        if (Sme >= kk && Snx < kk) { s_sel = t; s_kk = kk - Snx; }
        __syncthreads();
        pref |= (unsigned)s_sel << (bp * 8);
        msk  |= 0xFFu << (bp * 8);
        kk = s_kk;
        __syncthreads();
    }

    // stable tie-break: keep first kk elements equal to threshold (index order)
    int ec = 0;
#pragma unroll
    for (int j = 0; j < 4; ++j) ec += (ab[j] == pref) ? 1 : 0;
    sscan[t] = ec;
    __syncthreads();
    for (int o = 1; o < 256; o <<= 1) {               // inclusive prefix sum
        const int add = (t >= o) ? sscan[t - o] : 0;
        __syncthreads();
        sscan[t] += add;
        __syncthreads();
    }
    int excl = sscan[t] - ec;
#pragma unroll
    for (int j = 0; j < 4; ++j) {
        const bool eq = (ab[j] == pref);
        const bool kp = (ab[j] > pref) || (eq && (excl < kk));
        o1r[2048 + t * 4 + j] = kp ? fv[j] : 0.0f;
        if (eq) ++excl;
    }
}

// ---------------------------------------------------------------------------
extern "C" void kernel_launch(void* const* d_in, const int* in_sizes, int n_in,
                              void* d_out, int out_size, void* d_ws, size_t ws_size,
                              hipStream_t stream)
{
    const float* SG   = (const float*)d_in[0];
    const float* SL   = (const float*)d_in[1];
    const float* VIS  = (const float*)d_in[2];
    const float* Wgu1 = (const float*)d_in[3];  const float* bgu1 = (const float*)d_in[4];
    const float* Wgu2 = (const float*)d_in[5];  const float* bgu2 = (const float*)d_in[6];
    const float* Wgd1 = (const float*)d_in[7];  const float* bgd1 = (const float*)d_in[8];
    const float* Wgd2 = (const float*)d_in[9];  const float* bgd2 = (const float*)d_in[10];
    const float* Wlu1 = (const float*)d_in[11]; const float* blu1 = (const float*)d_in[12];
    const float* Wlu2 = (const float*)d_in[13]; const float* blu2 = (const float*)d_in[14];
    const float* Wld1 = (const float*)d_in[15]; const float* bld1 = (const float*)d_in[16];
    const float* Wld2 = (const float*)d_in[17]; const float* bld2 = (const float*)d_in[18];
    const float* Wo   = (const float*)d_in[19]; const float* bo   = (const float*)d_in[20];
    const float* Win  = (const float*)d_in[21]; const float* bin_ = (const float*)d_in[22];
    const float* Wv = Win + (size_t)2 * 1024 * 1024;   // Win[2E:]
    const float* bv = bin_ + 2048;

    float* OUT1 = (float*)d_out;                         // B x 3072
    float* OUT2 = OUT1 + (size_t)16384 * 3072;           // B x 1024 (final)
    float* OUT3 = OUT2 + (size_t)16384 * 1024;           // B x 1024 (f2)

    // ws: bf16 weights + concat'd biases (~21 MB)
    char* ws = (char*)d_ws;
    bf16_t* Wbf = (bf16_t*)ws;                           // 10M bf16
    float*  bb  = (float*)(ws + 20971520);               // 4096 f32

    // activation scratch lives inside d_out region 1 (192 MB) — all dead
    // before finalize_topk fully overwrites it.
    bf16_t* X  = (bf16_t*)d_out;                         // 32 MB (sg path)
    bf16_t* Y  = X + (size_t)16384 * 1024;               // 32 MB (sl path), contiguous with X
    bf16_t* U  = (bf16_t*)((char*)d_out + 67108864);     // 32 MB (gate pre-act)
    bf16_t* H1 = (bf16_t*)((char*)d_out + 100663296);    // 64 MB (hidden, N=2048)
    bf16_t* V  = H1;                                     // 64 MB, reuses H1 after G6

    WSrcs srcs;
    srcs.p[0] = Wgu1; srcs.p[1] = Wgd1; srcs.p[2] = Wlu1; srcs.p[3] = Wld1;
    srcs.p[4] = Wgu2; srcs.p[5] = Wgd2; srcs.p[6] = Wlu2; srcs.p[7] = Wld2;
    srcs.p[8] = Wv;   srcs.p[9] = Wo;

    cast_weights<<<10240, 256, 0, stream>>>(srcs, Wbf);
    concat_bias<<<8, 256, 0, stream>>>(bgu1, bgd1, bb);
    concat_bias<<<8, 256, 0, stream>>>(blu1, bld1, bb + 2048);
    cast_act<<<16384, 256, 0, stream>>>(SG, X);
    cast_act<<<16384, 256, 0, stream>>>(SL, Y);

    bf16_t* Wg1   = Wbf;                                 // [Wgu1;Wgd1] 2048x1024
    bf16_t* Wl1   = Wbf + (size_t)2 * 1048576;           // [Wlu1;Wld1]
    bf16_t* Wgu2b = Wbf + (size_t)4 * 1048576;
    bf16_t* Wgd2b = Wbf + (size_t)5 * 1048576;
    bf16_t* Wlu2b = Wbf + (size_t)6 * 1048576;
    bf16_t* Wld2b = Wbf + (size_t)7 * 1048576;
    bf16_t* Wvb   = Wbf + (size_t)8 * 1048576;
    bf16_t* Wob   = Wbf + (size_t)9 * 1048576;

    dim3 blk(256);
    // global path
    gemm_bt<0><<<dim3(16, 128), blk, 0, stream>>>(X, 1024, Wg1, bb, nullptr, H1, 2048, 1024);
    gemm_bt<1><<<dim3(8, 128),  blk, 0, stream>>>(H1, 2048, Wgu2b, bgu2, nullptr, U, 1024, 1024);
    gemm_bt<2><<<dim3(8, 128),  blk, 0, stream>>>(H1 + 1024, 2048, Wgd2b, bgd2, U, X, 1024, 1024);
    // local path
    gemm_bt<0><<<dim3(16, 128), blk, 0, stream>>>(Y, 1024, Wl1, bb + 2048, nullptr, H1, 2048, 1024);
    gemm_bt<1><<<dim3(8, 128),  blk, 0, stream>>>(H1, 2048, Wlu2b, blu2, nullptr, U, 1024, 1024);
    gemm_bt<2><<<dim3(8, 128),  blk, 0, stream>>>(H1 + 1024, 2048, Wld2b, bld2, U, Y, 1024, 1024);
    // attn_out, batched M=32768 over [sg;sl]
    gemm_bt<1><<<dim3(8, 256),  blk, 0, stream>>>(X, 1024, Wvb, bv, nullptr, V, 1024, 1024);
    gemm_bt<3><<<dim3(8, 256),  blk, 0, stream>>>(V, 1024, Wob, bo, nullptr, OUT2, 1024, 1024);

    finalize_topk<<<16384, 256, 0, stream>>>(OUT2, OUT3, VIS, OUT1);
}